// Round 1
// baseline (395.467 us; speedup 1.0000x reference)
//
#include <hip/hip_runtime.h>

#define T_STEPS 256
#define BATCH   128
#define DIM     1024
#define HID     1024

// ---------- prep: row sums of Wh ----------
__global__ __launch_bounds__(256) void k_rowsum(const float* __restrict__ Wh,
                                                float* __restrict__ whsum) {
    int j = blockIdx.x;                       // one block per row
    const float4* row = (const float4*)(Wh + (size_t)j * HID);
    float4 vv = row[threadIdx.x];             // 256 threads * 4 = 1024
    float s = vv.x + vv.y + vv.z + vv.w;
    for (int off = 32; off; off >>= 1) s += __shfl_down(s, off, 64);
    __shared__ float ls[4];
    if ((threadIdx.x & 63) == 0) ls[threadIdx.x >> 6] = s;
    __syncthreads();
    if (threadIdx.x == 0) whsum[j] = ls[0] + ls[1] + ls[2] + ls[3];
}

// ---------- prep: M = Wq @ Wi  [4, DIM] ----------
__global__ __launch_bounds__(256) void k_M(const float* __restrict__ Wq,
                                           const float* __restrict__ Wi,
                                           float* __restrict__ M) {
    int d = blockIdx.x * 256 + threadIdx.x;   // 4 blocks cover DIM
    float a0 = 0.f, a1 = 0.f, a2 = 0.f, a3 = 0.f;
    for (int j = 0; j < HID; j++) {
        float wv = Wi[(size_t)j * DIM + d];   // coalesced over threads
        a0 += Wq[0 * HID + j] * wv;           // uniform -> s_load
        a1 += Wq[1 * HID + j] * wv;
        a2 += Wq[2 * HID + j] * wv;
        a3 += Wq[3 * HID + j] * wv;
    }
    M[0 * DIM + d] = a0;
    M[1 * DIM + d] = a1;
    M[2 * DIM + d] = a2;
    M[3 * DIM + d] = a3;
}

// ---------- prep: v = Wq@whsum ; cb = Wq@(bi+bh) + bq + theta ----------
__global__ __launch_bounds__(64) void k_combine(const float* __restrict__ Wq,
                                                const float* __restrict__ whsum,
                                                const float* __restrict__ bi,
                                                const float* __restrict__ bh,
                                                const float* __restrict__ bq,
                                                const float* __restrict__ theta,
                                                float* __restrict__ v,
                                                float* __restrict__ cb) {
    int tid = threadIdx.x;                    // single wave
    float accv[4] = {0.f, 0.f, 0.f, 0.f};
    float accc[4] = {0.f, 0.f, 0.f, 0.f};
    for (int j = tid; j < HID; j += 64) {
        float ws = whsum[j];
        float bb = bi[j] + bh[j];
        #pragma unroll
        for (int w = 0; w < 4; w++) {
            float q = Wq[w * HID + j];
            accv[w] += q * ws;
            accc[w] += q * bb;
        }
    }
    #pragma unroll
    for (int w = 0; w < 4; w++) {
        for (int off = 32; off; off >>= 1) {
            accv[w] += __shfl_xor(accv[w], off, 64);
            accc[w] += __shfl_xor(accc[w], off, 64);
        }
    }
    if (tid == 0) {
        #pragma unroll
        for (int w = 0; w < 4; w++) {
            v[w]  = accv[w];
            cb[w] = accc[w] + bq[w] + theta[w];
        }
    }
}

// ---------- qx = inputs @ M.T   [T*B, 4] ; wave per row ----------
__global__ __launch_bounds__(256) void k_qx(const float* __restrict__ x,
                                            const float* __restrict__ M,
                                            float* __restrict__ qx) {
    int gtid   = blockIdx.x * blockDim.x + threadIdx.x;
    int wave   = gtid >> 6;
    int lane   = threadIdx.x & 63;
    int nwaves = (gridDim.x * blockDim.x) >> 6;

    // M fragment held in registers: m[w][k] covers element w*DIM + k*256 + lane*4 ..+3
    float4 m[4][4];
    #pragma unroll
    for (int w = 0; w < 4; w++)
        #pragma unroll
        for (int k = 0; k < 4; k++)
            m[w][k] = *(const float4*)(M + w * DIM + k * 256 + lane * 4);

    for (int r = wave; r < T_STEPS * BATCH; r += nwaves) {
        const float4* row = (const float4*)(x + (size_t)r * DIM);
        float a0 = 0.f, a1 = 0.f, a2 = 0.f, a3 = 0.f;
        #pragma unroll
        for (int k = 0; k < 4; k++) {
            float4 xv = row[k * 64 + lane];   // contiguous 1 KB per instruction
            a0 += xv.x * m[0][k].x + xv.y * m[0][k].y + xv.z * m[0][k].z + xv.w * m[0][k].w;
            a1 += xv.x * m[1][k].x + xv.y * m[1][k].y + xv.z * m[1][k].z + xv.w * m[1][k].w;
            a2 += xv.x * m[2][k].x + xv.y * m[2][k].y + xv.z * m[2][k].z + xv.w * m[2][k].w;
            a3 += xv.x * m[3][k].x + xv.y * m[3][k].y + xv.z * m[3][k].z + xv.w * m[3][k].w;
        }
        for (int off = 32; off; off >>= 1) {
            a0 += __shfl_down(a0, off, 64);
            a1 += __shfl_down(a1, off, 64);
            a2 += __shfl_down(a2, off, 64);
            a3 += __shfl_down(a3, off, 64);
        }
        if (lane == 0) ((float4*)qx)[r] = make_float4(a0, a1, a2, a3);
    }
}

// ---------- sequential recurrence: thread per batch element ----------
__device__ __forceinline__ float fast_tanh(float x) {
    float e = __expf(2.f * x);
    return (e - 1.f) * __builtin_amdgcn_rcpf(e + 1.f);
}

__global__ __launch_bounds__(128) void k_rec(const float* __restrict__ qx,
                                             const float* __restrict__ vp,
                                             const float* __restrict__ cbp,
                                             float* __restrict__ hseq,
                                             float* __restrict__ cfin) {
    int b = threadIdx.x;                      // 128 threads, one block
    float v0 = vp[0], v1 = vp[1], v2 = vp[2], v3 = vp[3];
    float b0 = cbp[0], b1 = cbp[1], b2 = cbp[2], b3 = cbp[3];
    float h = 0.f, c = 0.f;
    for (int t = 0; t < T_STEPS; t++) {
        float4 q = ((const float4*)qx)[t * BATCH + b];
        float z0 = __cosf(q.x + b0 + h * v0);
        float z1 = __cosf(q.y + b1 + h * v1);
        float z2 = __cosf(q.z + b2 + h * v2);
        float z3 = __cosf(q.w + b3 + h * v3);
        // exps from CNOT-chain Z-expectations (analytic)
        float e1  = z0 * z1;
        float e2  = e1 * z2;
        float e3  = e2 * z3;
        float e0  = z1 * z2 * z3;
        float x0 = __expf(e0), x1 = __expf(e1), x2 = __expf(e2), x3 = __expf(e3);
        float inv = __builtin_amdgcn_rcpf(x0 + x1 + x2 + x3);
        float f  = x0 * inv;
        float i_ = x1 * inv;
        float g  = x2 * inv;
        float o  = x3 * inv;
        c = f * c + i_ * fast_tanh(g);
        h = o * fast_tanh(c);
        hseq[t * BATCH + b] = h;
    }
    cfin[b] = c;
}

// ---------- broadcast write of ys / hx / cx ----------
__global__ __launch_bounds__(256) void k_write(const float* __restrict__ hseq,
                                               const float* __restrict__ cfin,
                                               float* __restrict__ out) {
    int r = blockIdx.x;
    float val;
    size_t off;
    const size_t YS = (size_t)T_STEPS * BATCH * HID;
    if (r < T_STEPS * BATCH) {
        val = hseq[r];
        off = (size_t)r * HID;
    } else if (r < T_STEPS * BATCH + BATCH) {
        int b = r - T_STEPS * BATCH;
        val = hseq[(T_STEPS - 1) * BATCH + b];
        off = YS + (size_t)b * HID;
    } else {
        int b = r - T_STEPS * BATCH - BATCH;
        val = cfin[b];
        off = YS + (size_t)BATCH * HID + (size_t)b * HID;
    }
    float4 vv = make_float4(val, val, val, val);
    ((float4*)(out + off))[threadIdx.x] = vv;  // 256 * 16B = 1024 floats
}

extern "C" void kernel_launch(void* const* d_in, const int* in_sizes, int n_in,
                              void* d_out, int out_size, void* d_ws, size_t ws_size,
                              hipStream_t stream) {
    const float* inputs = (const float*)d_in[0];
    const float* Wi     = (const float*)d_in[1];
    const float* bi     = (const float*)d_in[2];
    const float* Wh     = (const float*)d_in[3];
    const float* bh     = (const float*)d_in[4];
    const float* Wq     = (const float*)d_in[5];
    const float* bq     = (const float*)d_in[6];
    const float* theta  = (const float*)d_in[7];
    float* out = (float*)d_out;
    float* ws  = (float*)d_ws;

    // scratch layout in d_ws (~152 KB)
    float* whsum = ws;                    // 1024
    float* v     = ws + 1024;             // 4
    float* cb    = ws + 1028;             // 4
    float* M     = ws + 1088;             // 4096 (16B aligned)
    float* hseq  = ws + 1088 + 4096;      // 32768 (16B aligned)
    float* cfin  = hseq + 32768;          // 128
    // qx (131072 floats) lives at the head of d_out; k_write overwrites it after k_rec reads it
    float* qx = out;

    k_rowsum <<<1024, 256, 0, stream>>>(Wh, whsum);
    k_M      <<<4,    256, 0, stream>>>(Wq, Wi, M);
    k_combine<<<1,     64, 0, stream>>>(Wq, whsum, bi, bh, bq, theta, v, cb);
    k_qx     <<<256,  256, 0, stream>>>(inputs, M, qx);
    k_rec    <<<1,    128, 0, stream>>>(qx, v, cb, hseq, cfin);
    k_write  <<<T_STEPS * BATCH + 2 * BATCH, 256, 0, stream>>>(hseq, cfin, out);
}

// Round 2
// 326.575 us; speedup vs baseline: 1.2110x; 1.2110x over previous
//
#include <hip/hip_runtime.h>

#define T_STEPS 256
#define BATCH   128
#define DIM     1024
#define HID     1024
#define NJC     16   // j-chunks for M partials

// ---------- prep: row sums of Wh ----------
__global__ __launch_bounds__(256) void k_rowsum(const float* __restrict__ Wh,
                                                float* __restrict__ whsum) {
    int j = blockIdx.x;                       // one block per row
    const float4* row = (const float4*)(Wh + (size_t)j * HID);
    float4 vv = row[threadIdx.x];             // 256 threads * 4 = 1024
    float s = vv.x + vv.y + vv.z + vv.w;
    for (int off = 32; off; off >>= 1) s += __shfl_down(s, off, 64);
    __shared__ float ls[4];
    if ((threadIdx.x & 63) == 0) ls[threadIdx.x >> 6] = s;
    __syncthreads();
    if (threadIdx.x == 0) whsum[j] = ls[0] + ls[1] + ls[2] + ls[3];
}

// ---------- prep: Mpart[jc][w][d] partial sums of Wq @ Wi ----------
__global__ __launch_bounds__(256) void k_Mpart(const float* __restrict__ Wq,
                                               const float* __restrict__ Wi,
                                               float* __restrict__ Mpart) {
    int jc = blockIdx.x >> 2;                 // 0..15
    int db = blockIdx.x & 3;                  // 0..3
    int d  = db * 256 + threadIdx.x;
    float a0 = 0.f, a1 = 0.f, a2 = 0.f, a3 = 0.f;
    int j0 = jc * (HID / NJC);
    #pragma unroll 4
    for (int j = j0; j < j0 + HID / NJC; j++) {
        float wv = Wi[(size_t)j * DIM + d];   // coalesced over threads
        a0 += Wq[0 * HID + j] * wv;           // uniform -> scalar loads
        a1 += Wq[1 * HID + j] * wv;
        a2 += Wq[2 * HID + j] * wv;
        a3 += Wq[3 * HID + j] * wv;
    }
    float* base = Mpart + (size_t)jc * 4 * DIM;
    base[0 * DIM + d] = a0;
    base[1 * DIM + d] = a1;
    base[2 * DIM + d] = a2;
    base[3 * DIM + d] = a3;
}

// ---------- prep: reduce Mpart -> M [4, DIM] ----------
__global__ __launch_bounds__(256) void k_Mred(const float* __restrict__ Mpart,
                                              float* __restrict__ M) {
    int w = blockIdx.x >> 2;                  // 0..3
    int db = blockIdx.x & 3;
    int d  = db * 256 + threadIdx.x;
    float s = 0.f;
    #pragma unroll
    for (int jc = 0; jc < NJC; jc++)
        s += Mpart[(size_t)jc * 4 * DIM + w * DIM + d];
    M[w * DIM + d] = s;
}

// ---------- prep: v = Wq@whsum ; cb = Wq@(bi+bh) + bq + theta ----------
__global__ __launch_bounds__(64) void k_combine(const float* __restrict__ Wq,
                                                const float* __restrict__ whsum,
                                                const float* __restrict__ bi,
                                                const float* __restrict__ bh,
                                                const float* __restrict__ bq,
                                                const float* __restrict__ theta,
                                                float* __restrict__ v,
                                                float* __restrict__ cb) {
    int tid = threadIdx.x;                    // single wave
    float accv[4] = {0.f, 0.f, 0.f, 0.f};
    float accc[4] = {0.f, 0.f, 0.f, 0.f};
    for (int j = tid; j < HID; j += 64) {
        float ws = whsum[j];
        float bb = bi[j] + bh[j];
        #pragma unroll
        for (int w = 0; w < 4; w++) {
            float q = Wq[w * HID + j];
            accv[w] += q * ws;
            accc[w] += q * bb;
        }
    }
    #pragma unroll
    for (int w = 0; w < 4; w++) {
        for (int off = 32; off; off >>= 1) {
            accv[w] += __shfl_xor(accv[w], off, 64);
            accc[w] += __shfl_xor(accc[w], off, 64);
        }
    }
    if (tid == 0) {
        #pragma unroll
        for (int w = 0; w < 4; w++) {
            v[w]  = accv[w];
            cb[w] = accc[w] + bq[w] + theta[w];
        }
    }
}

// ---------- qx = inputs @ M.T   [T*B, 4] ; wave per row, grid-stride ----------
__global__ __launch_bounds__(256) void k_qx(const float* __restrict__ x,
                                            const float* __restrict__ M,
                                            float* __restrict__ qx) {
    int gtid   = blockIdx.x * blockDim.x + threadIdx.x;
    int wave   = gtid >> 6;
    int lane   = threadIdx.x & 63;
    int nwaves = (gridDim.x * blockDim.x) >> 6;

    // M fragment in registers: m[w][k] covers element w*DIM + k*256 + lane*4 ..+3
    float4 m[4][4];
    #pragma unroll
    for (int w = 0; w < 4; w++)
        #pragma unroll
        for (int k = 0; k < 4; k++)
            m[w][k] = *(const float4*)(M + w * DIM + k * 256 + lane * 4);

    for (int r = wave; r < T_STEPS * BATCH; r += nwaves) {
        const float4* row = (const float4*)(x + (size_t)r * DIM);
        float a0 = 0.f, a1 = 0.f, a2 = 0.f, a3 = 0.f;
        #pragma unroll
        for (int k = 0; k < 4; k++) {
            float4 xv = row[k * 64 + lane];   // contiguous 1 KB per instruction
            a0 += xv.x * m[0][k].x + xv.y * m[0][k].y + xv.z * m[0][k].z + xv.w * m[0][k].w;
            a1 += xv.x * m[1][k].x + xv.y * m[1][k].y + xv.z * m[1][k].z + xv.w * m[1][k].w;
            a2 += xv.x * m[2][k].x + xv.y * m[2][k].y + xv.z * m[2][k].z + xv.w * m[2][k].w;
            a3 += xv.x * m[3][k].x + xv.y * m[3][k].y + xv.z * m[3][k].z + xv.w * m[3][k].w;
        }
        for (int off = 32; off; off >>= 1) {
            a0 += __shfl_down(a0, off, 64);
            a1 += __shfl_down(a1, off, 64);
            a2 += __shfl_down(a2, off, 64);
            a3 += __shfl_down(a3, off, 64);
        }
        if (lane == 0) ((float4*)qx)[r] = make_float4(a0, a1, a2, a3);
    }
}

// ---------- sequential recurrence: thread per batch element ----------
__device__ __forceinline__ float fast_tanh(float x) {
    float e = __expf(2.f * x);
    return (e - 1.f) * __builtin_amdgcn_rcpf(e + 1.f);
}

__global__ __launch_bounds__(128) void k_rec(const float* __restrict__ qx,
                                             const float* __restrict__ vp,
                                             const float* __restrict__ cbp,
                                             float* __restrict__ hseq,
                                             float* __restrict__ cfin) {
    int b = threadIdx.x;                      // 128 threads, one block
    float v0 = vp[0], v1 = vp[1], v2 = vp[2], v3 = vp[3];
    float b0 = cbp[0], b1 = cbp[1], b2 = cbp[2], b3 = cbp[3];
    float h = 0.f, c = 0.f;
    float4 q = ((const float4*)qx)[b];        // prefetch t=0
    for (int t = 0; t < T_STEPS; t++) {
        float4 qn;
        if (t + 1 < T_STEPS) qn = ((const float4*)qx)[(t + 1) * BATCH + b];
        float z0 = __cosf(q.x + b0 + h * v0);
        float z1 = __cosf(q.y + b1 + h * v1);
        float z2 = __cosf(q.z + b2 + h * v2);
        float z3 = __cosf(q.w + b3 + h * v3);
        // exps from CNOT-chain Z-expectations (analytic)
        float e1  = z0 * z1;
        float e2  = e1 * z2;
        float e3  = e2 * z3;
        float e0  = z1 * z2 * z3;
        float x0 = __expf(e0), x1 = __expf(e1), x2 = __expf(e2), x3 = __expf(e3);
        float inv = __builtin_amdgcn_rcpf(x0 + x1 + x2 + x3);
        float f  = x0 * inv;
        float i_ = x1 * inv;
        float g  = x2 * inv;
        float o  = x3 * inv;
        c = f * c + i_ * fast_tanh(g);
        h = o * fast_tanh(c);
        hseq[t * BATCH + b] = h;
        q = qn;
    }
    cfin[b] = c;
}

// ---------- broadcast write of ys / hx / cx ----------
__global__ __launch_bounds__(256) void k_write(const float* __restrict__ hseq,
                                               const float* __restrict__ cfin,
                                               float* __restrict__ out) {
    int r = blockIdx.x;
    float val;
    size_t off;
    const size_t YS = (size_t)T_STEPS * BATCH * HID;
    if (r < T_STEPS * BATCH) {
        val = hseq[r];
        off = (size_t)r * HID;
    } else if (r < T_STEPS * BATCH + BATCH) {
        int b = r - T_STEPS * BATCH;
        val = hseq[(T_STEPS - 1) * BATCH + b];
        off = YS + (size_t)b * HID;
    } else {
        int b = r - T_STEPS * BATCH - BATCH;
        val = cfin[b];
        off = YS + (size_t)BATCH * HID + (size_t)b * HID;
    }
    float4 vv = make_float4(val, val, val, val);
    ((float4*)(out + off))[threadIdx.x] = vv;  // 256 * 16B = 1024 floats
}

extern "C" void kernel_launch(void* const* d_in, const int* in_sizes, int n_in,
                              void* d_out, int out_size, void* d_ws, size_t ws_size,
                              hipStream_t stream) {
    const float* inputs = (const float*)d_in[0];
    const float* Wi     = (const float*)d_in[1];
    const float* bi     = (const float*)d_in[2];
    const float* Wh     = (const float*)d_in[3];
    const float* bh     = (const float*)d_in[4];
    const float* Wq     = (const float*)d_in[5];
    const float* bq     = (const float*)d_in[6];
    const float* theta  = (const float*)d_in[7];
    float* out = (float*)d_out;
    float* ws  = (float*)d_ws;

    // scratch layout in d_ws
    float* whsum = ws;                         // 1024
    float* v     = ws + 1024;                  // 4
    float* cb    = ws + 1028;                  // 4
    float* M     = ws + 1088;                  // 4096
    float* hseq  = ws + 1088 + 4096;           // 32768
    float* cfin  = hseq + 32768;               // 128
    float* Mpart = cfin + 128;                 // 16*4*1024 = 65536
    // qx (131072 floats) lives at the head of d_out; k_write overwrites it after k_rec reads it
    float* qx = out;

    k_rowsum <<<1024, 256, 0, stream>>>(Wh, whsum);
    k_Mpart  <<<64,   256, 0, stream>>>(Wq, Wi, Mpart);
    k_Mred   <<<16,   256, 0, stream>>>(Mpart, M);
    k_combine<<<1,     64, 0, stream>>>(Wq, whsum, bi, bh, bq, theta, v, cb);
    k_qx     <<<1024, 256, 0, stream>>>(inputs, M, qx);
    k_rec    <<<1,    128, 0, stream>>>(qx, v, cb, hseq, cfin);
    k_write  <<<T_STEPS * BATCH + 2 * BATCH, 256, 0, stream>>>(hseq, cfin, out);
}